// Round 9
// baseline (31170.923 us; speedup 1.0000x reference)
//
#include <hip/hip_runtime.h>
#include <math.h>

#define NBLK 256
#define NTHR 256

typedef float f32x4 __attribute__((ext_vector_type(4)));

// ---------------- coherent (cross-XCD, L2-bypass) access helpers ----------------
__device__ __forceinline__ float2 ld2a(const float* p){
    unsigned long long u = __hip_atomic_load((const unsigned long long*)p,
                                             __ATOMIC_RELAXED, __HIP_MEMORY_SCOPE_AGENT);
    float2 r;
    r.x = __uint_as_float((unsigned)u);
    r.y = __uint_as_float((unsigned)(u >> 32));
    return r;
}
__device__ __forceinline__ void st2a(float* p, float a, float b){
    unsigned long long u = (unsigned long long)__float_as_uint(a)
                         | ((unsigned long long)__float_as_uint(b) << 32);
    __hip_atomic_store((unsigned long long*)p, u,
                       __ATOMIC_RELAXED, __HIP_MEMORY_SCOPE_AGENT);
}
__device__ __forceinline__ void st1a(float* p, float v){
    __hip_atomic_store((unsigned*)p, __float_as_uint(v), __ATOMIC_RELAXED, __HIP_MEMORY_SCOPE_AGENT);
}

__device__ __forceinline__ float fsigmoid(float x){ return 1.0f/(1.0f + __expf(-x)); }
__device__ __forceinline__ float ftanh(float x){
    float e = __expf(2.0f*x);          // inf-safe
    return 1.0f - 2.0f/(e + 1.0f);
}
__device__ __forceinline__ float dot4(f32x4 a, f32x4 b){
    return a.x*b.x + a.y*b.y + a.z*b.z + a.w*b.w;
}

struct Params {
    const float* input_p; const float* mask_p; const float* input_q; const float* mask_q;
    const float* W_ih; const float* W_hh; const float* bias;
    const float* ln_i_g; const float* ln_i_b; const float* ln_h_g; const float* ln_h_b;
    const float* ln_c_g; const float* ln_c_b;
    const float* Wq; const float* Wp; const float* Wr; const float* w_att; const float* b_att;
    float* out;
    float* qWq;    // [2][2048][768] read-only in coop
    float* iqT;    // [16][768][128] read-only
    float* pWp0;   // [b*128+t][768]
    float* pWih0;  // [b*128+t][3072]
    float* h;      // [2][16][768] coherent
    float* c;      // coherent, contiguous after h
    float* sF0;    // [16][768]
    float* sF1h;   // [16][768]
    float* sF1c;   // [16][768]
    float* whF0;   // [16][3072]
    float* whF1;   // [16][3072]
    float* cwF1;   // [16][3072]
    float* wiF0;   // [16][3072]
    float* wiF1;   // [16][3072]
    float* wghtd0; // [16][768]
    float* wghtd1; // [16][768]
    unsigned* bar;
};

// ------------- monotonic tree barrier (256 blocks = 16 leaves x 16) -------------
__device__ __forceinline__ void gsync(unsigned* bar, int bid, unsigned n){
    __syncthreads();
    if (threadIdx.x == 0){
        unsigned* leaf = bar + 128 + (bid >> 4)*32;
        unsigned old = __hip_atomic_fetch_add(leaf, 1u, __ATOMIC_RELAXED, __HIP_MEMORY_SCOPE_AGENT);
        if ((old & 15u) == 15u){
            unsigned rold = __hip_atomic_fetch_add(bar + 32, 1u, __ATOMIC_RELAXED, __HIP_MEMORY_SCOPE_AGENT);
            if ((rold & 15u) == 15u){
                __hip_atomic_store(bar, n + 1u, __ATOMIC_RELEASE, __HIP_MEMORY_SCOPE_AGENT);
            }
        }
        int spins = 0;
        while (__hip_atomic_load(bar, __ATOMIC_RELAXED, __HIP_MEMORY_SCOPE_AGENT) < n + 1u){
            __builtin_amdgcn_s_sleep(4);
            if (++spins > 1024){
                (void)__hip_atomic_load(bar, __ATOMIC_ACQUIRE, __HIP_MEMORY_SCOPE_AGENT);
                spins = 0;
            }
        }
    }
    __syncthreads();
}

__device__ __forceinline__ float bsum4(float v, float* red, int tid){
    #pragma unroll
    for (int off = 32; off; off >>= 1) v += __shfl_xor(v, off);
    __syncthreads();
    if ((tid & 63) == 0) red[tid >> 6] = v;
    __syncthreads();
    float s = red[0]+red[1]+red[2]+red[3];
    __syncthreads();
    return s;
}

// Weights-in-registers persistent kernel.
// Owner blocks 0..183 hold 96 cols x 768 k of one weight matrix in 288 VGPRs/thread.
// thread: colg = tid>>4 (6 cols), kg = tid&15 (k = i*64 + kg*4 + j, i<12, j<4).
__global__ __launch_bounds__(NTHR, 1) void coop_kernel(Params p)
{
    __shared__ float smem[12292];
    const int tid = threadIdx.x;
    const int bid = blockIdx.x;
    const int colg = tid >> 4, kg = tid & 15;
    unsigned n = 0;

    // ---- role table ----
    int m = 0; const float* Wsrc = nullptr; int WN = 0; int C0 = 0;
    if      (bid < 8)   { m=1; Wsrc=p.Wr;                                        WN=768;  C0=bid*96; }
    else if (bid < 40)  { m=2; Wsrc=p.W_hh;                                      WN=3072; C0=(bid-8)*96; }
    else if (bid < 72)  { m=3; Wsrc=p.W_ih + (size_t)768*3072;                   WN=3072; C0=(bid-40)*96; }
    else if (bid < 80)  { m=4; Wsrc=p.Wr + (size_t)589824;                       WN=768;  C0=(bid-72)*96; }
    else if (bid < 88)  { m=5; Wsrc=p.Wp + (size_t)589824;                       WN=768;  C0=(bid-80)*96; }
    else if (bid < 120) { m=6; Wsrc=p.W_hh + (size_t)2359296;                    WN=3072; C0=(bid-88)*96; }
    else if (bid < 152) { m=7; Wsrc=p.W_ih + (size_t)4718592;                    WN=3072; C0=(bid-120)*96; }
    else if (bid < 184) { m=8; Wsrc=p.W_ih + (size_t)4718592 + (size_t)768*3072; WN=3072; C0=(bid-152)*96; }
    const int colbase = C0 + colg*6;

    // ---- one-time weight load into registers (static indexing only) ----
    float w2[288];
    if (m){
        #pragma unroll
        for (int i = 0; i < 12; i++){
            #pragma unroll
            for (int j = 0; j < 4; j++){
                const float* src = Wsrc + (size_t)(i*64 + kg*4 + j)*WN + colbase;
                float2 a0 = *(const float2*)(src);
                float2 a1 = *(const float2*)(src + 2);
                float2 a2 = *(const float2*)(src + 4);
                int o = (i*4 + j)*6;
                w2[o+0]=a0.x; w2[o+1]=a0.y; w2[o+2]=a1.x;
                w2[o+3]=a1.y; w2[o+4]=a2.x; w2[o+5]=a2.y;
            }
        }
    }

    // stage 16x768 f32 operand (h or weighted) into LDS, coherent
    auto stage_in = [&](const float* src){
        #pragma unroll
        for (int rep = 0; rep < 24; rep++){
            int i2 = tid + rep*256;
            float2 v = ld2a(src + (size_t)i2*2);
            smem[i2*2]   = v.x;
            smem[i2*2+1] = v.y;
        }
        __syncthreads();
    };

    // owner matmul: out[16][Ncols] final (full-k), shfl-reduced over kg
    auto mm_own = [&](float* outB, int Ncols){
        for (int r = 0; r < 16; r++){
            const float* Arow = smem + r*768 + (kg << 2);
            f32x4 hv[12];
            #pragma unroll
            for (int i = 0; i < 12; i++) hv[i] = *(const f32x4*)(Arow + i*64);
            float a0=0,a1=0,a2=0,a3=0,a4=0,a5=0;
            #pragma unroll
            for (int i = 0; i < 12; i++){
                #pragma unroll
                for (int j = 0; j < 4; j++){
                    float hvv = hv[i][j];
                    int o = (i*4 + j)*6;
                    a0 = fmaf(w2[o+0], hvv, a0); a1 = fmaf(w2[o+1], hvv, a1);
                    a2 = fmaf(w2[o+2], hvv, a2); a3 = fmaf(w2[o+3], hvv, a3);
                    a4 = fmaf(w2[o+4], hvv, a4); a5 = fmaf(w2[o+5], hvv, a5);
                }
            }
            #pragma unroll
            for (int s = 1; s <= 8; s <<= 1){
                a0 += __shfl_xor(a0, s); a1 += __shfl_xor(a1, s);
                a2 += __shfl_xor(a2, s); a3 += __shfl_xor(a3, s);
                a4 += __shfl_xor(a4, s); a5 += __shfl_xor(a5, s);
            }
            if (kg == 0){
                float* o = outB + (size_t)r*Ncols + colbase;
                st1a(o+0, a0); st1a(o+1, a1); st1a(o+2, a2);
                st1a(o+3, a3); st1a(o+4, a4); st1a(o+5, a5);
            }
        }
        __syncthreads();
    };

    // fused attention for batch b = bid-184
    auto attn = [&](int d, int t, const float* sA, const float* sB, float* wout){
        int b = bid - 184;
        float* s_sh  = smem;
        float* wa_sh = smem + 768;
        float* e_sh  = smem + 1536;   // 132
        if (tid < 192){
            f32x4 acc = *(const f32x4*)(p.b_att + d*768 + tid*4);
            if (d == 0)
                acc += *(const f32x4*)(p.pWp0 + ((size_t)b*128 + t)*768 + tid*4);
            float2 u0 = ld2a(sA + b*768 + tid*4);
            float2 u1 = ld2a(sA + b*768 + tid*4 + 2);
            acc.x += u0.x; acc.y += u0.y; acc.z += u1.x; acc.w += u1.y;
            if (sB){
                float2 v0 = ld2a(sB + b*768 + tid*4);
                float2 v1 = ld2a(sB + b*768 + tid*4 + 2);
                acc.x += v0.x; acc.y += v0.y; acc.z += v1.x; acc.w += v1.y;
            }
            *(f32x4*)&s_sh[tid*4] = acc;
        } else {
            int i0 = tid - 192;
            for (int rr = 0; rr < 3; rr++){
                int i = i0 + rr*64;
                *(f32x4*)&wa_sh[i*4] = *(const f32x4*)(p.w_att + d*768 + i*4);
            }
        }
        __syncthreads();
        {
            int sq = tid >> 1, half = tid & 1;
            const float* qrow = p.qWq + ((size_t)(d*2048 + b*128 + sq))*768 + half*384;
            const float* ss = s_sh + half*384;
            const float* ww = wa_sh + half*384;
            float part = 0.f;
            #pragma unroll 4
            for (int i = 0; i < 96; i++){
                f32x4 q  = *(const f32x4*)(qrow + i*4);
                f32x4 s4 = *(const f32x4*)(ss + i*4);
                f32x4 w4 = *(const f32x4*)(ww + i*4);
                part += ftanh(q.x + s4.x)*w4.x + ftanh(q.y + s4.y)*w4.y
                      + ftanh(q.z + s4.z)*w4.z + ftanh(q.w + s4.w)*w4.w;
            }
            part += __shfl_xor(part, 1);
            if (half == 0){
                e_sh[sq] = (p.mask_q[b*128 + sq] > 0.f) ? __expf(part) : 0.f;
            }
        }
        __syncthreads();
        if (tid < 64){
            float v = e_sh[tid] + e_sh[tid + 64];
            #pragma unroll
            for (int off = 32; off; off >>= 1) v += __shfl_xor(v, off);
            if (tid == 0) e_sh[128] = 1.0f / v;
        }
        __syncthreads();
        float inv = e_sh[128];
        #pragma unroll
        for (int rep = 0; rep < 3; rep++){
            int cc = tid + rep*256;
            const float* ip = p.iqT + ((size_t)b*768 + cc)*128;
            float acc = 0.f;
            #pragma unroll 8
            for (int j = 0; j < 32; j++){
                f32x4 q  = *(const f32x4*)(ip + j*4);
                f32x4 e4 = *(const f32x4*)&e_sh[j*4];
                acc += dot4(q, e4);
            }
            st1a(wout + b*768 + cc, acc*inv);
        }
        __syncthreads();
    };

    // LN + gates for batch b = bid-200
    auto gates = [&](int d, int t){
        int b = bid - 200;
        float* wi_sh = smem;
        float* wh_sh = smem + 3072;
        float* c_sh  = smem + 6144;
        float* red   = smem + 6928;
        const float mmv = p.mask_p[b*128 + t];
        const float* gi = p.ln_i_g + d*3072; const float* bi = p.ln_i_b + d*3072;
        const float* gh = p.ln_h_g + d*3072; const float* bh = p.ln_h_b + d*3072;
        const float* gc = p.ln_c_g + d*768;  const float* bc = p.ln_c_b + d*768;
        const float* bias_d = p.bias + d*3072;
        const float* wiF = d ? p.wiF1 : p.wiF0;
        const float* whF = d ? p.whF1 : p.whF0;

        float swi=0,qwi=0,swh=0,qwh=0;
        #pragma unroll
        for (int rep = 0; rep < 3; rep++){
            int j4 = tid + rep*256;
            int base = b*3072 + j4*4;
            float2 u0 = ld2a(wiF + base), u1 = ld2a(wiF + base + 2);
            f32x4 a = { u0.x, u0.y, u1.x, u1.y };
            if (d == 0){
                a += *(const f32x4*)(p.pWih0 + ((size_t)b*128 + t)*3072 + j4*4);
            } else {
                float2 c0 = ld2a(p.cwF1 + base), c1 = ld2a(p.cwF1 + base + 2);
                a.x += c0.x; a.y += c0.y; a.z += c1.x; a.w += c1.y;
            }
            float2 h0 = ld2a(whF + base), h1 = ld2a(whF + base + 2);
            f32x4 hvec = { h0.x, h0.y, h1.x, h1.y };
            *(f32x4*)&wi_sh[j4*4] = a;
            *(f32x4*)&wh_sh[j4*4] = hvec;
            swi += a.x+a.y+a.z+a.w;   qwi += dot4(a,a);
            swh += hvec.x+hvec.y+hvec.z+hvec.w; qwh += dot4(hvec,hvec);
        }
        swi = bsum4(swi, red, tid);
        qwi = bsum4(qwi, red, tid);
        swh = bsum4(swh, red, tid);
        qwh = bsum4(qwh, red, tid);
        float mi = swi/3072.f, vi = fmaxf((qwi - 3072.f*mi*mi)/3071.f, 0.f);
        float mh = swh/3072.f, vh = fmaxf((qwh - 3072.f*mh*mh)/3071.f, 0.f);
        float ivi = 1.f/(sqrtf(vi + 1e-6f) + 1e-6f);
        float ivh = 1.f/(sqrtf(vh + 1e-6f) + 1e-6f);

        for (int j = tid; j < 3072; j += NTHR){
            float pre = mmv*(gi[j]*(wi_sh[j]-mi)*ivi + bi[j])
                      + mmv*(gh[j]*(wh_sh[j]-mh)*ivh + bh[j])
                      + bias_d[j];
            wi_sh[j] = pre;
        }
        __syncthreads();

        float sc=0,qc=0;
        for (int idx = tid; idx < 384; idx += NTHR){
            int u = idx*2;
            float2 c_old = ld2a(p.c + (size_t)d*12288 + b*768 + u);
            float f0  = wi_sh[u],        f1  = wi_sh[u+1];
            float i0  = wi_sh[768+u],    i1  = wi_sh[768+u+1];
            float g0  = wi_sh[2304+u],   g1  = wi_sh[2304+u+1];
            float c10 = fsigmoid(f0)*c_old.x + fsigmoid(i0)*ftanh(g0);
            float c11 = fsigmoid(f1)*c_old.y + fsigmoid(i1)*ftanh(g1);
            c10 = c10*mmv + c_old.x*(1.f - mmv);
            c11 = c11*mmv + c_old.y*(1.f - mmv);
            st2a(p.c + (size_t)d*12288 + b*768 + u, c10, c11);
            c_sh[u] = c10; c_sh[u+1] = c11;
            sc += c10 + c11; qc += c10*c10 + c11*c11;
        }
        sc = bsum4(sc, red, tid);
        qc = bsum4(qc, red, tid);
        float mc = sc/768.f, vc = fmaxf((qc - 768.f*mc*mc)/767.f, 0.f);
        float ivc = 1.f/(sqrtf(vc + 1e-6f) + 1e-6f);

        for (int idx = tid; idx < 384; idx += NTHR){
            int u = idx*2;
            float2 h_old = ld2a(p.h + (size_t)d*12288 + b*768 + u);
            float o0 = wi_sh[1536+u], o1 = wi_sh[1536+u+1];
            float l0 = (gc[u]*(c_sh[u]-mc)*ivc + bc[u])*mmv;
            float l1 = (gc[u+1]*(c_sh[u+1]-mc)*ivc + bc[u+1])*mmv;
            float h10 = fsigmoid(o0)*ftanh(l0);
            float h11 = fsigmoid(o1)*ftanh(l1);
            h10 = h10*mmv + h_old.x*(1.f - mmv);
            h11 = h11*mmv + h_old.y*(1.f - mmv);
            st2a(p.h + (size_t)d*12288 + b*768 + u, h10, h11);
            if (d == 1){
                float2 ov = { h10, h11 };
                *(float2*)(p.out + ((size_t)b*128 + t)*768 + u) = ov;
            }
        }
        __syncthreads();
    };

    // ---- prologue: zero h,c; write mask tail ----
    {
        int gid = bid*NTHR + tid;
        if (gid < 24576) st2a(p.h + (size_t)gid*2, 0.f, 0.f);
        if (gid < 2048)  p.out[(size_t)16*128*768 + gid] = p.mask_p[gid];
    }
    gsync(p.bar, bid, n); n++;

    for (int t = 0; t < 128; ++t){
        // A: M1,M2 (h0_prev), M4,M6 (h1_prev)
        if (m==1 || m==2 || m==4 || m==6){
            stage_in((m <= 2) ? p.h : p.h + 12288);
            float* ob = (m==1) ? p.sF0 : (m==2) ? p.whF0 : (m==4) ? p.sF1h : p.whF1;
            mm_own(ob, (m==1 || m==4) ? 768 : 3072);
        }
        gsync(p.bar, bid, n); n++;

        // B: attention d=0
        if (bid >= 184 && bid < 200) attn(0, t, p.sF0, nullptr, p.wghtd0);
        gsync(p.bar, bid, n); n++;

        // C: M3 (weighted0)
        if (m == 3){ stage_in(p.wghtd0); mm_own(p.wiF0, 3072); }
        gsync(p.bar, bid, n); n++;

        // D: gates d=0 -> h0,c0
        if (bid >= 200 && bid < 216) gates(0, t);
        gsync(p.bar, bid, n); n++;

        // E: M5,M7 (h0_new)
        if (m==5 || m==7){
            stage_in(p.h);
            if (m == 5) mm_own(p.sF1c, 768);
            else        mm_own(p.cwF1, 3072);
        }
        gsync(p.bar, bid, n); n++;

        // F: attention d=1
        if (bid >= 184 && bid < 200) attn(1, t, p.sF1h, p.sF1c, p.wghtd1);
        gsync(p.bar, bid, n); n++;

        // G: M8 (weighted1)
        if (m == 8){ stage_in(p.wghtd1); mm_own(p.wiF1, 3072); }
        gsync(p.bar, bid, n); n++;

        // H: gates d=1 -> h1,c1, out
        if (bid >= 200 && bid < 216) gates(1, t);
        gsync(p.bar, bid, n); n++;
    }
}

// ---------- precompute GEMM (f32 out; validated R0/R5/R7 kernel) ----------
__global__ __launch_bounds__(256) void k_mm_pre(
    const float* __restrict__ Ain, const float* __restrict__ W,
    float* __restrict__ C, int ldw, int ncols)
{
    __shared__ float Ash[16][772];
    int rowbase = blockIdx.y*16;
    for (int r = 0; r < 16; r++)
        for (int i = threadIdx.x; i < 768; i += 256)
            Ash[r][i] = Ain[(size_t)(rowbase + r)*768 + i];
    __syncthreads();
    int lane = threadIdx.x & 63;
    int colq = lane & 15, rsub = lane >> 4, wq = threadIdx.x >> 6;
    int r = wq*4 + rsub;
    int col = blockIdx.x*64 + colq*4;
    float4 acc = {0.f,0.f,0.f,0.f};
    const float* Wc = W + col;
    for (int k = 0; k < 768; k += 4){
        float4 a4 = *(const float4*)&Ash[r][k];
        float4 w0 = *(const float4*)(Wc + (size_t)(k+0)*ldw);
        float4 w1 = *(const float4*)(Wc + (size_t)(k+1)*ldw);
        float4 w2 = *(const float4*)(Wc + (size_t)(k+2)*ldw);
        float4 w3 = *(const float4*)(Wc + (size_t)(k+3)*ldw);
        acc.x += a4.x*w0.x + a4.y*w1.x + a4.z*w2.x + a4.w*w3.x;
        acc.y += a4.x*w0.y + a4.y*w1.y + a4.z*w2.y + a4.w*w3.y;
        acc.z += a4.x*w0.z + a4.y*w1.z + a4.z*w2.z + a4.w*w3.z;
        acc.w += a4.x*w0.w + a4.y*w1.w + a4.z*w2.w + a4.w*w3.w;
    }
    *(float4*)(C + (size_t)(rowbase + r)*ncols + col) = acc;
}

// ---------- transpose input_q -> iqT[b][c][sq] f32 ----------
__global__ __launch_bounds__(256) void k_transq(
    const float* __restrict__ iq, float* __restrict__ iqT)
{
    __shared__ float Tsh[32][136];
    int c0 = blockIdx.x*32, b = blockIdx.y;
    for (int rep = 0; rep < 4; rep++){
        int idx = threadIdx.x + rep*256;
        int sq = idx >> 3, cq = idx & 7;
        float4 v = *(const float4*)(iq + ((size_t)b*128 + sq)*768 + c0 + cq*4);
        Tsh[cq*4+0][sq] = v.x;
        Tsh[cq*4+1][sq] = v.y;
        Tsh[cq*4+2][sq] = v.z;
        Tsh[cq*4+3][sq] = v.w;
    }
    __syncthreads();
    for (int rep = 0; rep < 4; rep++){
        int idx = threadIdx.x + rep*256;
        int cl = idx >> 5, sq4 = (idx & 31)*4;
        float4 v = *(const float4*)&Tsh[cl][sq4];
        *(float4*)(iqT + ((size_t)b*768 + c0 + cl)*128 + sq4) = v;
    }
}

extern "C" void kernel_launch(void* const* d_in, const int* in_sizes, int n_in,
                              void* d_out, int out_size, void* d_ws, size_t ws_size,
                              hipStream_t stream)
{
    (void)in_sizes; (void)n_in; (void)out_size; (void)ws_size;
    Params P;
    P.input_p = (const float*)d_in[0];
    P.mask_p  = (const float*)d_in[1];
    P.input_q = (const float*)d_in[2];
    P.mask_q  = (const float*)d_in[3];
    P.W_ih    = (const float*)d_in[4];
    P.W_hh    = (const float*)d_in[5];
    P.bias    = (const float*)d_in[6];
    P.ln_i_g  = (const float*)d_in[7];
    P.ln_i_b  = (const float*)d_in[8];
    P.ln_h_g  = (const float*)d_in[9];
    P.ln_h_b  = (const float*)d_in[10];
    P.ln_c_g  = (const float*)d_in[11];
    P.ln_c_b  = (const float*)d_in[12];
    P.Wq      = (const float*)d_in[13];
    P.Wp      = (const float*)d_in[14];
    P.Wr      = (const float*)d_in[15];
    P.w_att   = (const float*)d_in[16];
    P.b_att   = (const float*)d_in[17];
    P.out     = (float*)d_out;

    float* ws = (float*)d_ws;
    size_t off = 0;
    auto alloc = [&](size_t nfloat)->float*{
        float* r = ws + off;
        off += (nfloat + 63) & ~(size_t)63;
        return r;
    };
    P.qWq    = alloc((size_t)2*2048*768);
    P.iqT    = alloc((size_t)16*768*128);
    P.pWp0   = alloc((size_t)2048*768);
    P.pWih0  = alloc((size_t)2048*3072);
    P.h      = alloc(24576);
    P.c      = alloc(24576);          // contiguous after h
    P.sF0    = alloc(12288);
    P.sF1h   = alloc(12288);
    P.sF1c   = alloc(12288);
    P.whF0   = alloc(49152);
    P.whF1   = alloc(49152);
    P.cwF1   = alloc(49152);
    P.wiF0   = alloc(49152);
    P.wiF1   = alloc(49152);
    P.wghtd0 = alloc(12288);
    P.wghtd1 = alloc(12288);
    P.bar    = (unsigned*)alloc(2048);

    hipMemsetAsync((void*)P.bar, 0, 2048*sizeof(unsigned), stream);
    k_mm_pre<<<dim3(12,128), 256, 0, stream>>>(P.input_q, P.Wq, P.qWq, 768, 768);
    k_mm_pre<<<dim3(12,128), 256, 0, stream>>>(P.input_q, P.Wq + (size_t)589824,
                                               P.qWq + (size_t)2048*768, 768, 768);
    k_mm_pre<<<dim3(12,128), 256, 0, stream>>>(P.input_p, P.Wp, P.pWp0, 768, 768);
    k_mm_pre<<<dim3(48,128), 256, 0, stream>>>(P.input_p, P.W_ih, P.pWih0, 3072, 3072);
    k_transq<<<dim3(24,16), 256, 0, stream>>>(P.input_q, P.iqT);
    coop_kernel<<<dim3(NBLK), dim3(NTHR), 0, stream>>>(P);
}

// Round 10
// 28169.821 us; speedup vs baseline: 1.1065x; 1.1065x over previous
//
#include <hip/hip_runtime.h>
#include <math.h>

#define NBLK 768
#define NTHR 256

typedef float f32x4 __attribute__((ext_vector_type(4)));

// ---------------- coherent (cross-XCD, L2-bypass) access helpers ----------------
__device__ __forceinline__ float2 ld2a(const float* p){
    unsigned long long u = __hip_atomic_load((const unsigned long long*)p,
                                             __ATOMIC_RELAXED, __HIP_MEMORY_SCOPE_AGENT);
    float2 r;
    r.x = __uint_as_float((unsigned)u);
    r.y = __uint_as_float((unsigned)(u >> 32));
    return r;
}
__device__ __forceinline__ void st2a(float* p, float a, float b){
    unsigned long long u = (unsigned long long)__float_as_uint(a)
                         | ((unsigned long long)__float_as_uint(b) << 32);
    __hip_atomic_store((unsigned long long*)p, u,
                       __ATOMIC_RELAXED, __HIP_MEMORY_SCOPE_AGENT);
}
__device__ __forceinline__ float ld1a(const float* p){
    unsigned u = __hip_atomic_load((const unsigned*)p, __ATOMIC_RELAXED, __HIP_MEMORY_SCOPE_AGENT);
    return __uint_as_float(u);
}
__device__ __forceinline__ void st1a(float* p, float v){
    __hip_atomic_store((unsigned*)p, __float_as_uint(v), __ATOMIC_RELAXED, __HIP_MEMORY_SCOPE_AGENT);
}

__device__ __forceinline__ float fsigmoid(float x){ return 1.0f/(1.0f + __expf(-x)); }
__device__ __forceinline__ float ftanh(float x){
    float e = __expf(2.0f*x);          // inf-safe
    return 1.0f - 2.0f/(e + 1.0f);
}
__device__ __forceinline__ float dot4(f32x4 a, f32x4 b){
    return a.x*b.x + a.y*b.y + a.z*b.z + a.w*b.w;
}

struct Params {
    const float* input_p; const float* mask_p; const float* input_q; const float* mask_q;
    const float* W_ih; const float* W_hh; const float* bias;
    const float* ln_i_g; const float* ln_i_b; const float* ln_h_g; const float* ln_h_b;
    const float* ln_c_g; const float* ln_c_b;
    const float* Wq; const float* Wp; const float* Wr; const float* w_att; const float* b_att;
    float* out;
    float* qWq;    // [2][2048][768] read-only in coop
    float* iqT;    // [16][768][128] read-only
    float* pWp0;   // [b*128+t][768]
    float* pWih0;  // [b*128+t][3072]
    float* h;      // [2][16][768] coherent
    float* c;      // coherent, contiguous after h
    float* sP;     // [24][16][768]  (0-11: h@Wr ; 12-23: cur@Wp d=1)
    float* whP;    // [12][16][3072]
    float* cwP;    // [12][16][3072]
    float* wiP;    // [4][16][3072]
    float* whR;    // [16][3072]
    float* cwR;    // [16][3072]
    float* wghtd;  // [16][768]
    float* escore; // [16][128]
    unsigned* bar;
};

// ---------- monotonic tree barrier (768 blocks = 48 leaves x 16) ----------
__device__ __forceinline__ void gsync(unsigned* bar, int bid, unsigned n){
    __syncthreads();
    if (threadIdx.x == 0){
        unsigned* leaf = bar + 128 + (bid >> 4)*32;
        unsigned old = __hip_atomic_fetch_add(leaf, 1u, __ATOMIC_RELAXED, __HIP_MEMORY_SCOPE_AGENT);
        if ((old & 15u) == 15u){
            unsigned rold = __hip_atomic_fetch_add(bar + 32, 1u, __ATOMIC_RELAXED, __HIP_MEMORY_SCOPE_AGENT);
            if ((rold % 48u) == 47u){
                __hip_atomic_store(bar, n + 1u, __ATOMIC_RELEASE, __HIP_MEMORY_SCOPE_AGENT);
            }
        }
        int spins = 0;
        while (__hip_atomic_load(bar, __ATOMIC_RELAXED, __HIP_MEMORY_SCOPE_AGENT) < n + 1u){
            __builtin_amdgcn_s_sleep(4);
            if (++spins > 1024){
                (void)__hip_atomic_load(bar, __ATOMIC_ACQUIRE, __HIP_MEMORY_SCOPE_AGENT);
                spins = 0;
            }
        }
    }
    __syncthreads();
}

// stage A[16][64] coherent slice into LDS, padded stride 68
__device__ __forceinline__ void stageA64(const float* src, int k0, float* Ash, int tid){
    #pragma unroll
    for (int rep = 0; rep < 2; rep++){
        int i2 = tid + rep*256;              // 512 f2 chunks, 32 per row
        int r = i2 >> 5, kk = (i2 & 31)*2;
        float2 v = ld2a(src + (size_t)r*768 + k0 + kk);
        Ash[r*68 + kk]     = v.x;
        Ash[r*68 + kk + 1] = v.y;
    }
    __syncthreads();
}

// stage A[16][192] coherent slice into LDS, padded stride 196
__device__ __forceinline__ void stageA192(const float* src, int k0, float* Ash, int tid){
    #pragma unroll
    for (int rep = 0; rep < 6; rep++){
        int i2 = tid + rep*256;              // 1536 f2 chunks, 96 per row
        int r = i2 / 96, kk = (i2 % 96)*2;
        float2 v = ld2a(src + (size_t)r*768 + k0 + kk);
        Ash[r*196 + kk]     = v.x;
        Ash[r*196 + kk + 1] = v.y;
    }
    __syncthreads();
}

// 128-col tile, K=64 partial: thread = 1 row x 8 cols, 8-k bursts (16 loads in flight)
__device__ __forceinline__ void mm64(
    const float* W, int N, float* outP, int cbase, int k0,
    const float* Ash, int tid)
{
    int cg = tid & 15, rg = tid >> 4;
    int col = cbase + cg*8;
    const float* Wc = W + (size_t)k0*N + col;
    const float* Arow = Ash + rg*68;
    f32x4 acc0 = {0,0,0,0}, acc1 = {0,0,0,0};
    for (int kb = 0; kb < 64; kb += 8){
        f32x4 wa[8], wb[8];
        #pragma unroll
        for (int j = 0; j < 8; j++){
            wa[j] = *(const f32x4*)(Wc + (size_t)(kb+j)*N);
            wb[j] = *(const f32x4*)(Wc + (size_t)(kb+j)*N + 4);
        }
        #pragma unroll
        for (int j = 0; j < 8; j++){
            float a = Arow[kb + j];
            acc0 += a*wa[j];
            acc1 += a*wb[j];
        }
    }
    float* o = outP + (size_t)rg*N + col;
    st2a(o,   acc0.x, acc0.y); st2a(o+2, acc0.z, acc0.w);
    st2a(o+4, acc1.x, acc1.y); st2a(o+6, acc1.z, acc1.w);
    __syncthreads();
}

// 64-col tile, K=192 partial: thread = 1 row x 4 cols, 8-k bursts
__device__ __forceinline__ void mm192(
    const float* W, int N, float* outP, int cbase, int k0,
    const float* Ash, int tid)
{
    int cg = tid & 15, rg = tid >> 4;
    int col = cbase + cg*4;
    const float* Wc = W + (size_t)k0*N + col;
    const float* Arow = Ash + rg*196;
    f32x4 acc = {0,0,0,0};
    for (int kb = 0; kb < 192; kb += 8){
        f32x4 w[8];
        #pragma unroll
        for (int j = 0; j < 8; j++)
            w[j] = *(const f32x4*)(Wc + (size_t)(kb+j)*N);
        #pragma unroll
        for (int j = 0; j < 8; j++)
            acc += Arow[kb + j]*w[j];
    }
    float* o = outP + (size_t)rg*N + col;
    st2a(o,   acc.x, acc.y); st2a(o+2, acc.z, acc.w);
    __syncthreads();
}

__device__ __forceinline__ float bsum4(float v, float* red, int tid){
    #pragma unroll
    for (int off = 32; off; off >>= 1) v += __shfl_xor(v, off);
    __syncthreads();
    if ((tid & 63) == 0) red[tid >> 6] = v;
    __syncthreads();
    float s = red[0]+red[1]+red[2]+red[3];
    __syncthreads();
    return s;
}

__global__ __launch_bounds__(NTHR, 3) void coop_kernel(Params p)
{
    __shared__ float smem[6936];
    const int tid = threadIdx.x;
    const int bid = blockIdx.x;
    unsigned n = 0;

    {
        int gid = bid*NTHR + tid;
        if (gid < 24576) st2a(p.h + (size_t)gid*2, 0.f, 0.f);   // h then c contiguous
        if (gid < 2048)  p.out[(size_t)16*128*768 + gid] = p.mask_p[gid];
    }
    gsync(p.bar, bid, n); n++;

    for (int t = 0; t < 128; ++t){
        for (int d = 0; d < 2; ++d){

            // ===== S1: h weight matmuls, KC=64, k-split 12, 128-col tiles =====
            // d0: 30 tiles (6 Wr0 + 24 Whh0) x12 = 360 blocks
            // d1: 60 tiles (6 Wr1 + 6 Wp1 + 24 Whh1 + 24 Wih1cur) x12 = 720 blocks
            {
                int nblk = (d == 0) ? 360 : 720;
                if (bid < nblk){
                    int tile = bid / 12, kc = bid % 12, k0 = kc*64;
                    if (d == 0){
                        stageA64(p.h, k0, smem, tid);
                        if (tile < 6)
                            mm64(p.Wr, 768, p.sP + (size_t)kc*12288, tile*128, k0, smem, tid);
                        else
                            mm64(p.W_hh, 3072, p.whP + (size_t)kc*49152, (tile-6)*128, k0, smem, tid);
                    } else {
                        bool useH1 = (tile < 6) || (tile >= 12 && tile < 36);
                        stageA64(p.h + (useH1 ? 12288 : 0), k0, smem, tid);
                        if (tile < 6)
                            mm64(p.Wr + (size_t)589824, 768,
                                 p.sP + (size_t)kc*12288, tile*128, k0, smem, tid);
                        else if (tile < 12)
                            mm64(p.Wp + (size_t)589824, 768,
                                 p.sP + (size_t)(12+kc)*12288, (tile-6)*128, k0, smem, tid);
                        else if (tile < 36)
                            mm64(p.W_hh + (size_t)2359296, 3072,
                                 p.whP + (size_t)kc*49152, (tile-12)*128, k0, smem, tid);
                        else
                            mm64(p.W_ih + (size_t)4718592, 3072,
                                 p.cwP + (size_t)kc*49152, (tile-36)*128, k0, smem, tid);
                    }
                }
            }
            gsync(p.bar, bid, n); n++;

            // ===== S2a: scores (512 blocks: 32 per batch, 4 scores each) =====
            if (bid < 512){
                int b = bid >> 5, sq0 = (bid & 31)*4;
                float* s_sh  = smem;
                float* wa_sh = smem + 768;
                if (tid < 192){
                    f32x4 acc = *(const f32x4*)(p.b_att + d*768 + tid*4);
                    if (d == 0)
                        acc += *(const f32x4*)(p.pWp0 + ((size_t)b*128 + t)*768 + tid*4);
                    int ncp = (d == 0) ? 12 : 24;
                    for (int cp = 0; cp < ncp; cp++){
                        const float* src = p.sP + (size_t)cp*12288 + b*768 + tid*4;
                        float2 u0 = ld2a(src);
                        float2 u1 = ld2a(src + 2);
                        acc.x += u0.x; acc.y += u0.y; acc.z += u1.x; acc.w += u1.y;
                    }
                    *(f32x4*)&s_sh[tid*4] = acc;
                } else {
                    int i0 = tid - 192;
                    for (int rr = 0; rr < 3; rr++){
                        int i = i0 + rr*64;
                        *(f32x4*)&wa_sh[i*4] = *(const f32x4*)(p.w_att + d*768 + i*4);
                    }
                }
                __syncthreads();
                int sq = sq0 + (tid >> 6), l = tid & 63;
                const float* qrow = p.qWq + ((size_t)(d*2048 + b*128 + sq))*768 + l*12;
                const float* ss = s_sh + l*12;
                const float* ww = wa_sh + l*12;
                float part = 0.f;
                #pragma unroll
                for (int i = 0; i < 3; i++){
                    f32x4 q  = *(const f32x4*)(qrow + i*4);
                    f32x4 s4 = *(const f32x4*)(ss + i*4);
                    f32x4 w4 = *(const f32x4*)(ww + i*4);
                    part += ftanh(q.x + s4.x)*w4.x + ftanh(q.y + s4.y)*w4.y
                          + ftanh(q.z + s4.z)*w4.z + ftanh(q.w + s4.w)*w4.w;
                }
                #pragma unroll
                for (int off = 32; off; off >>= 1) part += __shfl_xor(part, off);
                if (l == 0){
                    float e = (p.mask_q[b*128 + sq] > 0.f) ? __expf(part) : 0.f;
                    st1a(p.escore + b*128 + sq, e);
                }
            }
            gsync(p.bar, bid, n); n++;

            // ===== S2b: weighted (64 blocks) + wh/cw 12->1 reduce (96 blocks) =====
            if (bid < 64){
                int b = bid >> 2, cg = bid & 3;
                float* e_sh = smem;    // 129
                if (tid < 128) e_sh[tid] = ld1a(p.escore + b*128 + tid);
                __syncthreads();
                if (tid < 64){
                    float v = e_sh[tid] + e_sh[tid + 64];
                    #pragma unroll
                    for (int off = 32; off; off >>= 1) v += __shfl_xor(v, off);
                    if (tid == 0) e_sh[128] = 1.0f / v;
                }
                __syncthreads();
                float inv = e_sh[128];
                if (tid < 192){
                    int cc = cg*192 + tid;
                    const float* ip = p.iqT + ((size_t)b*768 + cc)*128;
                    float acc = 0.f;
                    #pragma unroll 8
                    for (int j = 0; j < 32; j++){
                        f32x4 q  = *(const f32x4*)(ip + j*4);
                        f32x4 e4 = *(const f32x4*)&e_sh[j*4];
                        acc += dot4(q, e4);
                    }
                    st1a(p.wghtd + b*768 + cc, acc*inv);
                }
            } else if (bid < 160){
                int gid = (bid - 64)*NTHR + tid;         // < 24576
                int ntask = d ? 24576 : 12288;           // f4 tasks
                if (gid < ntask){
                    int which = gid >= 12288;
                    int i4 = which ? gid - 12288 : gid;
                    const float* src = which ? p.cwP : p.whP;
                    float* dst = which ? p.cwR : p.whR;
                    float2 a0 = {0.f,0.f}, a1 = {0.f,0.f};
                    #pragma unroll
                    for (int cp = 0; cp < 12; cp++){
                        const float* s0 = src + (size_t)cp*49152 + i4*4;
                        float2 u0 = ld2a(s0);
                        float2 u1 = ld2a(s0 + 2);
                        a0.x += u0.x; a0.y += u0.y; a1.x += u1.x; a1.y += u1.y;
                    }
                    st2a(dst + i4*4,     a0.x, a0.y);
                    st2a(dst + i4*4 + 2, a1.x, a1.y);
                }
            }
            gsync(p.bar, bid, n); n++;

            // ===== S3: wi matmul (48 x 64-col tiles x 4 kc = 192 blocks, KC=192) =====
            if (bid < 192){
                int tile = bid >> 2, kc = bid & 3, k0 = kc*192;
                stageA192(p.wghtd, k0, smem, tid);
                mm192(p.W_ih + (size_t)d*4718592 + (size_t)2359296, 3072,
                      p.wiP + (size_t)kc*49152, tile*64, k0, smem, tid);
            }
            gsync(p.bar, bid, n); n++;

            // ===== S4: LN + gates (16 blocks) =====
            if (bid < 16){
                const int b = bid;
                float* wi_sh = smem;           // 3072
                float* wh_sh = smem + 3072;    // 3072
                float* c_sh  = smem + 6144;    // 768
                float* red   = smem + 6928;    // 4
                const float mmv = p.mask_p[b*128 + t];
                const float* gi = p.ln_i_g + d*3072; const float* bi = p.ln_i_b + d*3072;
                const float* gh = p.ln_h_g + d*3072; const float* bh = p.ln_h_b + d*3072;
                const float* gc = p.ln_c_g + d*768;  const float* bc = p.ln_c_b + d*768;
                const float* bias_d = p.bias + d*3072;

                float swi=0,qwi=0,swh=0,qwh=0;
                #pragma unroll
                for (int rep = 0; rep < 3; rep++){
                    int j4 = tid + rep*256;
                    int base = b*3072 + j4*4;
                    f32x4 a = {0,0,0,0};
                    #pragma unroll
                    for (int cp = 0; cp < 4; cp++){
                        const float* s0 = p.wiP + (size_t)cp*49152 + base;
                        float2 u0 = ld2a(s0);
                        float2 u1 = ld2a(s0 + 2);
                        a.x += u0.x; a.y += u0.y; a.z += u1.x; a.w += u1.y;
                    }
                    if (d == 0){
                        a += *(const f32x4*)(p.pWih0 + ((size_t)b*128 + t)*3072 + j4*4);
                    } else {
                        float2 c0 = ld2a(p.cwR + base), c1 = ld2a(p.cwR + base + 2);
                        a.x += c0.x; a.y += c0.y; a.z += c1.x; a.w += c1.y;
                    }
                    float2 h0 = ld2a(p.whR + base), h1 = ld2a(p.whR + base + 2);
                    f32x4 hvec = { h0.x, h0.y, h1.x, h1.y };
                    *(f32x4*)&wi_sh[j4*4] = a;
                    *(f32x4*)&wh_sh[j4*4] = hvec;
                    swi += a.x+a.y+a.z+a.w;   qwi += dot4(a,a);
                    swh += hvec.x+hvec.y+hvec.z+hvec.w; qwh += dot4(hvec,hvec);
                }
                swi = bsum4(swi, red, tid);
                qwi = bsum4(qwi, red, tid);
                swh = bsum4(swh, red, tid);
                qwh = bsum4(qwh, red, tid);
                float mi = swi/3072.f, vi = fmaxf((qwi - 3072.f*mi*mi)/3071.f, 0.f);
                float mh = swh/3072.f, vh = fmaxf((qwh - 3072.f*mh*mh)/3071.f, 0.f);
                float ivi = 1.f/(sqrtf(vi + 1e-6f) + 1e-6f);
                float ivh = 1.f/(sqrtf(vh + 1e-6f) + 1e-6f);

                for (int j = tid; j < 3072; j += NTHR){
                    float pre = mmv*(gi[j]*(wi_sh[j]-mi)*ivi + bi[j])
                              + mmv*(gh[j]*(wh_sh[j]-mh)*ivh + bh[j])
                              + bias_d[j];
                    wi_sh[j] = pre;
                }
                __syncthreads();

                float sc=0,qc=0;
                for (int idx = tid; idx < 384; idx += NTHR){
                    int u = idx*2;
                    float2 c_old = ld2a(p.c + (size_t)d*12288 + b*768 + u);
                    float f0  = wi_sh[u],        f1  = wi_sh[u+1];
                    float i0  = wi_sh[768+u],    i1  = wi_sh[768+u+1];
                    float g0  = wi_sh[2304+u],   g1  = wi_sh[2304+u+1];
                    float c10 = fsigmoid(f0)*c_old.x + fsigmoid(i0)*ftanh(g0);
                    float c11 = fsigmoid(f1)*c_old.y + fsigmoid(i1)*ftanh(g1);
                    c10 = c10*mmv + c_old.x*(1.f - mmv);
                    c11 = c11*mmv + c_old.y*(1.f - mmv);
                    st2a(p.c + (size_t)d*12288 + b*768 + u, c10, c11);
                    c_sh[u] = c10; c_sh[u+1] = c11;
                    sc += c10 + c11; qc += c10*c10 + c11*c11;
                }
                sc = bsum4(sc, red, tid);
                qc = bsum4(qc, red, tid);
                float mc = sc/768.f, vc = fmaxf((qc - 768.f*mc*mc)/767.f, 0.f);
                float ivc = 1.f/(sqrtf(vc + 1e-6f) + 1e-6f);

                for (int idx = tid; idx < 384; idx += NTHR){
                    int u = idx*2;
                    float2 h_old = ld2a(p.h + (size_t)d*12288 + b*768 + u);
                    float o0 = wi_sh[1536+u], o1 = wi_sh[1536+u+1];
                    float l0 = (gc[u]*(c_sh[u]-mc)*ivc + bc[u])*mmv;
                    float l1 = (gc[u+1]*(c_sh[u+1]-mc)*ivc + bc[u+1])*mmv;
                    float h10 = fsigmoid(o0)*ftanh(l0);
                    float h11 = fsigmoid(o1)*ftanh(l1);
                    h10 = h10*mmv + h_old.x*(1.f - mmv);
                    h11 = h11*mmv + h_old.y*(1.f - mmv);
                    st2a(p.h + (size_t)d*12288 + b*768 + u, h10, h11);
                    if (d == 1){
                        float2 ov = { h10, h11 };
                        *(float2*)(p.out + ((size_t)b*128 + t)*768 + u) = ov;
                    }
                }
                __syncthreads();
            }
            gsync(p.bar, bid, n); n++;
        }
    }
}

// ---------- precompute GEMM (f32 out; validated R0/R5/R7 kernel) ----------
__global__ __launch_bounds__(256) void k_mm_pre(
    const float* __restrict__ Ain, const float* __restrict__ W,
    float* __restrict__ C, int ldw, int ncols)
{
    __shared__ float Ash[16][772];
    int rowbase = blockIdx.y*16;
    for (int r = 0; r < 16; r++)
        for (int i = threadIdx.x; i < 768; i += 256)
            Ash[r][i] = Ain[(size_t)(rowbase + r)*768 + i];
    __syncthreads();
    int lane = threadIdx.x & 63;
    int colq = lane & 15, rsub = lane >> 4, wq = threadIdx.x >> 6;
    int r = wq*4 + rsub;
    int col = blockIdx.x*64 + colq*4;
    float4 acc = {0.f,0.f,0.f,0.f};
    const float* Wc = W + col;
    for (int k = 0; k < 768; k += 4){
        float4 a4 = *(const float4*)&Ash[r][k];
        float4 w0 = *(const float4*)(Wc + (size_t)(k+0)*ldw);
        float4 w1 = *(const float4*)(Wc + (size_t)(k+1)*ldw);
        float4 w2 = *(const float4*)(Wc + (size_t)(k+2)*ldw);
        float4 w3 = *(const float4*)(Wc + (size_t)(k+3)*ldw);
        acc.x += a4.x*w0.x + a4.y*w1.x + a4.z*w2.x + a4.w*w3.x;
        acc.y += a4.x*w0.y + a4.y*w1.y + a4.z*w2.y + a4.w*w3.y;
        acc.z += a4.x*w0.z + a4.y*w1.z + a4.z*w2.z + a4.w*w3.z;
        acc.w += a4.x*w0.w + a4.y*w1.w + a4.z*w2.w + a4.w*w3.w;
    }
    *(float4*)(C + (size_t)(rowbase + r)*ncols + col) = acc;
}

// ---------- transpose input_q -> iqT[b][c][sq] f32 ----------
__global__ __launch_bounds__(256) void k_transq(
    const float* __restrict__ iq, float* __restrict__ iqT)
{
    __shared__ float Tsh[32][136];
    int c0 = blockIdx.x*32, b = blockIdx.y;
    for (int rep = 0; rep < 4; rep++){
        int idx = threadIdx.x + rep*256;
        int sq = idx >> 3, cq = idx & 7;
        float4 v = *(const float4*)(iq + ((size_t)b*128 + sq)*768 + c0 + cq*4);
        Tsh[cq*4+0][sq] = v.x;
        Tsh[cq*4+1][sq] = v.y;
        Tsh[cq*4+2][sq] = v.z;
        Tsh[cq*4+3][sq] = v.w;
    }
    __syncthreads();
    for (int rep = 0; rep < 4; rep++){
        int idx = threadIdx.x + rep*256;
        int cl = idx >> 5, sq4 = (idx & 31)*4;
        float4 v = *(const float4*)&Tsh[cl][sq4];
        *(float4*)(iqT + ((size_t)b*768 + c0 + cl)*128 + sq4) = v;
    }
}

extern "C" void kernel_launch(void* const* d_in, const int* in_sizes, int n_in,
                              void* d_out, int out_size, void* d_ws, size_t ws_size,
                              hipStream_t stream)
{
    (void)in_sizes; (void)n_in; (void)out_size; (void)ws_size;
    Params P;
    P.input_p = (const float*)d_in[0];
    P.mask_p  = (const float*)d_in[1];
    P.input_q = (const float*)d_in[2];
    P.mask_q  = (const float*)d_in[3];
    P.W_ih    = (const float*)d_in[4];
    P.W_hh    = (const float*)d_in[5];
    P.bias    = (const float*)d_in[6];
    P.ln_i_g  = (const float*)d_in[7];
    P.ln_i_b  = (const float*)d_in[8];
    P.ln_h_g  = (const float*)d_in[9];
    P.ln_h_b  = (const float*)d_in[10];
    P.ln_c_g  = (const float*)d_in[11];
    P.ln_c_b  = (const float*)d_in[12];
    P.Wq      = (const float*)d_in[13];
    P.Wp      = (const float*)d_in[14];
    P.Wr      = (const float*)d_in[15];
    P.w_att   = (const float*)d_in[16];
    P.b_att   = (const float*)d_in[17];
    P.out     = (float*)d_out;

    float* ws = (float*)d_ws;
    size_t off = 0;
    auto alloc = [&](size_t nfloat)->float*{
        float* r = ws + off;
        off += (nfloat + 63) & ~(size_t)63;
        return r;
    };
    P.qWq    = alloc((size_t)2*2048*768);
    P.iqT    = alloc((size_t)16*768*128);
    P.pWp0   = alloc((size_t)2048*768);
    P.pWih0  = alloc((size_t)2048*3072);
    P.h      = alloc(24576);
    P.c      = alloc(24576);          // contiguous after h
    P.sP     = alloc((size_t)24*12288);
    P.whP    = alloc((size_t)12*49152);
    P.cwP    = alloc((size_t)12*49152);
    P.wiP    = alloc((size_t)4*49152);
    P.whR    = alloc(49152);
    P.cwR    = alloc(49152);
    P.wghtd  = alloc(12288);
    P.escore = alloc(2048);
    P.bar    = (unsigned*)alloc(2048);

    hipMemsetAsync((void*)P.bar, 0, 2048*sizeof(unsigned), stream);
    k_mm_pre<<<dim3(12,128), 256, 0, stream>>>(P.input_q, P.Wq, P.qWq, 768, 768);
    k_mm_pre<<<dim3(12,128), 256, 0, stream>>>(P.input_q, P.Wq + (size_t)589824,
                                               P.qWq + (size_t)2048*768, 768, 768);
    k_mm_pre<<<dim3(12,128), 256, 0, stream>>>(P.input_p, P.Wp, P.pWp0, 768, 768);
    k_mm_pre<<<dim3(48,128), 256, 0, stream>>>(P.input_p, P.W_ih, P.pWih0, 3072, 3072);
    k_transq<<<dim3(24,16), 256, 0, stream>>>(P.input_q, P.iqT);
    coop_kernel<<<dim3(NBLK), dim3(NTHR), 0, stream>>>(P);
}